// Round 2
// baseline (3979.224 us; speedup 1.0000x reference)
//
#include <hip/hip_runtime.h>
#include <math.h>

typedef _Float16 f16;
typedef f16 f16x8 __attribute__((ext_vector_type(8)));
typedef float f32x4 __attribute__((ext_vector_type(4)));

#define B_ 8
#define D_ 256
#define T_ 8192
#define NQ 8
#define KB 1024
#define TT 64
#define NTHR 512
#define SCALE_UP 2048.0f
#define SCALE_DN 4.8828125e-4f        // 2^-11

#define OUT_CODES (B_ * D_ * T_)      // 16777216
#define OUT_BW (OUT_CODES + NQ * B_ * T_)
#define OUT_LOSS (OUT_BW + 1)

// rs: 64 rows x 512 halves (h1 granules 0..31, h2s granules 32..63),
// granule (8 halves) swizzled: stored at g ^ (t & 7). No pad.
#define R_BYTES 65536
#define RED_OFF R_BYTES               // redv[256] f32 (8 waves x 32 rows)
#define REDI_OFF (RED_OFF + 1024)     // redi[256] i32
#define WSUM_OFF (REDI_OFF + 1024)    // wsum[8]
#define LDS_TOTAL (WSUM_OFF + 32)     // 67648 -> 2 blocks/CU

// workspace layout
#define WS_HI (8192 * 4)              // csq first (32KB)
#define CBW_HALVES (NQ * 8 * KB * 32) // 2,097,152 halves per array
#define WS_LO (WS_HI + CBW_HALVES * 2)

// ---------------- init: codebook row norms (fp32) + scalar outputs ----------------
__global__ void init_cbsq_kernel(const float* __restrict__ cb, const int* __restrict__ sr,
                                 float* __restrict__ csq, float* __restrict__ out) {
    int gid = blockIdx.x * blockDim.x + threadIdx.x;
    int row = gid >> 6;
    int lane = gid & 63;
    float4 v = ((const float4*)(cb + (size_t)row * D_))[lane];
    float s = fmaf(v.x, v.x, fmaf(v.y, v.y, fmaf(v.z, v.z, v.w * v.w)));
#pragma unroll
    for (int off = 32; off; off >>= 1) s += __shfl_down(s, off);
    if (lane == 0) csq[row] = s;
    if (gid == 0) {
        out[OUT_BW] = (float)(*sr) * (80.0f / 1000.0f);
        out[OUT_LOSS] = 0.0f;
    }
}

// ---------------- init: split codebook into f16 hi + scaled-lo, [q][dc8][code][32] ----------------
__global__ void init_split_kernel(const float* __restrict__ cb, f16* __restrict__ whi,
                                  f16* __restrict__ wlo) {
    int gid = blockIdx.x * 256 + threadIdx.x;   // (q*8+dc)*1024 + k
    int qdc = gid >> 10, k = gid & 1023;
    int q = qdc >> 3, dc = qdc & 7;
    const float* src = cb + ((size_t)(q * 1024 + k)) * 256 + dc * 32;
    size_t wo = (size_t)gid * 32;
#pragma unroll
    for (int jj = 0; jj < 4; ++jj) {
        float4 a = ((const float4*)src)[jj * 2];
        float4 c = ((const float4*)src)[jj * 2 + 1];
        float vals[8] = {a.x, a.y, a.z, a.w, c.x, c.y, c.z, c.w};
        f16x8 hv, lv;
#pragma unroll
        for (int i = 0; i < 8; ++i) {
            f16 h = (f16)vals[i];
            hv[i] = h;
            lv[i] = (f16)((vals[i] - (float)h) * SCALE_UP);   // scaled lo: no f16 underflow
        }
        *(f16x8*)&whi[wo + jj * 8] = hv;
        *(f16x8*)&wlo[wo + jj * 8] = lv;
    }
}

// ---------------- main RVQ kernel: 3-product split-f16 MFMA GEMM ----------------
// 8 waves = 2 row-halves (wm) x 4 code-stripes (wn); 64 acc VGPR/wave -> target
// <=128 unified regs/wave -> 4 waves/SIMD (16/CU) at 2 blocks/CU.
extern "C" __global__ __launch_bounds__(NTHR, 4)
void rvq_kernel(const float* __restrict__ x, const float* __restrict__ cb,
                const float* __restrict__ csq, const f16* __restrict__ whi,
                const f16* __restrict__ wlo, float* __restrict__ out) {
    extern __shared__ char smem[];
    f16* rs = (f16*)smem;                          // [64][512] halves, granule-swizzled
    float* redv = (float*)(smem + RED_OFF);
    int* redi = (int*)(smem + REDI_OFF);
    float* wsum = (float*)(smem + WSUM_OFF);

    const int tid = threadIdx.x;
    const int w = tid >> 6;
    const int l = tid & 63;
    const int l15 = l & 15;
    const int q4 = l >> 4;
    const int wm = w >> 2;        // row half: rows [wm*32, wm*32+32)
    const int wn = w & 3;         // code stripe within sweep

    const int b = blockIdx.x >> 7;
    const int t0 = (blockIdx.x & 127) * TT;
    const float* xb = x + (size_t)b * D_ * T_;

    // residual init: rs[t][d] split of x[b][d][t0+t] (coalesced over t); swizzled store
    for (int d = tid >> 6; d < D_; d += 8) {
        float v = xb[(size_t)d * T_ + t0 + l];
        f16 h = (f16)v;
        const int sw = l & 7;
        rs[l * 512 + (((d >> 3) ^ sw) << 3) + (d & 7)] = h;
        rs[l * 512 + ((((d >> 3) + 32) ^ sw) << 3) + (d & 7)] = (f16)((v - (float)h) * SCALE_UP);
    }

    float ssq = 0.0f;

    for (int q = 0; q < NQ; ++q) {
        const float* cbq = cb + (size_t)q * KB * D_;
        const char* wq = (const char*)(whi + (size_t)q * 8 * KB * 32);
        const char* lq = (const char*)(wlo + (size_t)q * 8 * KB * 32);

        __syncthreads();   // rs ready (init or prev-q update); redv/redi free for this q

        // cross-sweep running best, per-lane registers (slot = (mt,rg) row ownership,
        // sweep-invariant; codes ascend across sweeps -> strict < keeps first min)
        float bval[8];
        int bidx[8];
#pragma unroll
        for (int e = 0; e < 8; ++e) { bval[e] = INFINITY; bidx[e] = 0; }

        const int swA = l15 & 7;                   // == t&7 for all A rows of this lane

        for (int s = 0; s < 4; ++s) {              // 4 sweeps of 256 codes; stripe/wave = 64
            // per-lane byte base into [code][32] tile: code*64 + q4*16
            const int vbase = ((s * 256 + wn * 64 + l15) << 6) + q4 * 16;

            f32x4 ah[2][4], am[2][4];              // 64 acc VGPRs
#pragma unroll
            for (int mt = 0; mt < 2; ++mt)
#pragma unroll
                for (int nt = 0; nt < 4; ++nt) { ah[mt][nt] = (f32x4)0.0f; am[mt][nt] = (f32x4)0.0f; }

#pragma unroll 1
            for (int dc = 0; dc < 8; ++dc) {
                const int ga = dc * 4 + q4;        // h1 granule (h2s = +32)
                f16x8 af1[2], af2[2];
#pragma unroll
                for (int mt = 0; mt < 2; ++mt) {
                    const f16* rowp = rs + (wm * 32 + mt * 16 + l15) * 512;
                    af1[mt] = *(const f16x8*)&rowp[(ga ^ swA) << 3];
                    af2[mt] = *(const f16x8*)&rowp[((ga + 32) ^ swA) << 3];
                }
                const char* wqd = wq + dc * 65536;
                const char* lqd = lq + dc * 65536;
#pragma unroll
                for (int nt = 0; nt < 4; ++nt) {
                    const int off = vbase + nt * 1024;
                    const f16x8 cb1 = *(const f16x8*)(wqd + off);
                    const f16x8 cb2 = *(const f16x8*)(lqd + off);
#pragma unroll
                    for (int mt = 0; mt < 2; ++mt) {
                        ah[mt][nt] = __builtin_amdgcn_mfma_f32_16x16x32_f16(af1[mt], cb1, ah[mt][nt], 0, 0, 0);
                        am[mt][nt] = __builtin_amdgcn_mfma_f32_16x16x32_f16(af2[mt], cb1, am[mt][nt], 0, 0, 0);
                        am[mt][nt] = __builtin_amdgcn_mfma_f32_16x16x32_f16(af1[mt], cb2, am[mt][nt], 0, 0, 0);
                    }
                }
            }
            // fold sweep into cross-sweep per-lane best (codes ascending -> strict <)
            const int cbase = s * 256 + wn * 64 + l15;
#pragma unroll
            for (int nt = 0; nt < 4; ++nt) {
                const int code = cbase + nt * 16;
                const float cq = csq[q * KB + code];
#pragma unroll
                for (int mt = 0; mt < 2; ++mt)
#pragma unroll
                    for (int rg = 0; rg < 4; ++rg) {
                        const float dot = fmaf(am[mt][nt][rg], SCALE_DN, ah[mt][nt][rg]);
                        const float dist = fmaf(-2.0f, dot, cq);
                        const int e = mt * 4 + rg;
                        if (dist < bval[e]) { bval[e] = dist; bidx[e] = code; }
                    }
            }
        }
        // once per q: butterfly across the 16 lanes sharing each row
#pragma unroll
        for (int m = 1; m < 16; m <<= 1) {
#pragma unroll
            for (int e = 0; e < 8; ++e) {
                const float ov = __shfl_xor(bval[e], m);
                const int oi = __shfl_xor(bidx[e], m);
                if (ov < bval[e] || (ov == bval[e] && oi < bidx[e])) { bval[e] = ov; bidx[e] = oi; }
            }
        }
        if (l15 == 0) {
#pragma unroll
            for (int mt = 0; mt < 2; ++mt)
#pragma unroll
                for (int rg = 0; rg < 4; ++rg) {
                    const int tl = mt * 16 + q4 * 4 + rg;   // row within wm half (C layout)
                    redv[w * 32 + tl] = bval[mt * 4 + rg];
                    redi[w * 32 + tl] = bidx[mt * 4 + rg];
                }
        }
        __syncthreads();   // all waves' redv/redi final; all GEMM rs reads done
        // merged final-reduce + residual update: thread -> (row t, 32-half chunk ch)
        {
            const int t = tid & 63, ch = tid >> 6;
            const int wmr = t >> 5, tl = t & 31;
            float bv = redv[(wmr * 4) * 32 + tl];
            int bi = redi[(wmr * 4) * 32 + tl];
#pragma unroll
            for (int w2 = 1; w2 < 4; ++w2) {
                const float v = redv[(wmr * 4 + w2) * 32 + tl];
                const int ii = redi[(wmr * 4 + w2) * 32 + tl];
                if (v < bv || (v == bv && ii < bi)) { bv = v; bi = ii; }
            }
            if (ch == 0) out[OUT_CODES + ((size_t)q * B_ + b) * T_ + t0 + t] = (float)bi;
            // residual update: fp32 = h1 + h2s*2^-11, subtract cb row, re-split; ssq
            const float* crow = cbq + (size_t)bi * D_ + ch * 32;
            f16* rowp = rs + t * 512;
            const int sw = t & 7;
#pragma unroll
            for (int jj = 0; jj < 4; ++jj) {
                const int g = ch * 4 + jj;
                const int g1 = (g ^ sw) << 3;
                const int g2 = ((g + 32) ^ sw) << 3;
                f16x8 hv = *(const f16x8*)&rowp[g1];
                f16x8 lv = *(const f16x8*)&rowp[g2];
                const float4 c0 = ((const float4*)crow)[jj * 2];
                const float4 c1 = ((const float4*)crow)[jj * 2 + 1];
                const float cc[8] = {c0.x, c0.y, c0.z, c0.w, c1.x, c1.y, c1.z, c1.w};
                f16x8 nh, nl;
#pragma unroll
                for (int i = 0; i < 8; ++i) {
                    const float r = fmaf((float)lv[i], SCALE_DN, (float)hv[i]);
                    const float nv = r - cc[i];
                    ssq = fmaf(nv, nv, ssq);
                    const f16 h = (f16)nv;
                    nh[i] = h;
                    nl[i] = (f16)((nv - (float)h) * SCALE_UP);
                }
                *(f16x8*)&rowp[g1] = nh;
                *(f16x8*)&rowp[g2] = nl;
            }
        }
        // next q's top __syncthreads orders rs writes before A-frag reads
    }
    __syncthreads();
    // quantized = x - r_final, [B][D][T], coalesced over t
    {
        float* outq = out + (size_t)b * D_ * T_;
        for (int d = tid >> 6; d < D_; d += 8) {
            const int sw = l & 7;
            const float h1 = (float)rs[l * 512 + (((d >> 3) ^ sw) << 3) + (d & 7)];
            const float h2 = (float)rs[l * 512 + ((((d >> 3) + 32) ^ sw) << 3) + (d & 7)];
            const size_t gi = (size_t)d * T_ + t0 + l;
            outq[gi] = xb[gi] - fmaf(h2, SCALE_DN, h1);
        }
    }
    // commit loss: wave reduce -> block reduce -> one atomic
#pragma unroll
    for (int off = 32; off; off >>= 1) ssq += __shfl_down(ssq, off);
    if (l == 0) wsum[w] = ssq;
    __syncthreads();
    if (tid == 0) {
        float tot = 0.0f;
#pragma unroll
        for (int i = 0; i < 8; ++i) tot += wsum[i];
        const float scale = 0.25f / ((float)NQ * (float)B_ * (float)D_ * (float)T_);
        atomicAdd(out + OUT_LOSS, tot * scale);
    }
}

extern "C" void kernel_launch(void* const* d_in, const int* in_sizes, int n_in,
                              void* d_out, int out_size, void* d_ws, size_t ws_size,
                              hipStream_t stream) {
    const float* x = (const float*)d_in[0];
    const int* sr = (const int*)d_in[1];
    const float* cb = (const float*)d_in[2];
    float* out = (float*)d_out;
    float* csq = (float*)d_ws;
    f16* whi = (f16*)((char*)d_ws + WS_HI);
    f16* wlo = (f16*)((char*)d_ws + WS_LO);

    hipFuncSetAttribute((const void*)rvq_kernel, hipFuncAttributeMaxDynamicSharedMemorySize,
                        LDS_TOTAL);

    init_cbsq_kernel<<<2048, 256, 0, stream>>>(cb, sr, csq, out);
    init_split_kernel<<<256, 256, 0, stream>>>(cb, whi, wlo);
    rvq_kernel<<<B_ * (T_ / TT), NTHR, LDS_TOTAL, stream>>>(x, cb, csq, whi, wlo, out);
}

// Round 3
// 1182.745 us; speedup vs baseline: 3.3644x; 3.3644x over previous
//
#include <hip/hip_runtime.h>
#include <math.h>

typedef _Float16 f16;
typedef f16 f16x8 __attribute__((ext_vector_type(8)));
typedef float f32x4 __attribute__((ext_vector_type(4)));

#define B_ 8
#define D_ 256
#define T_ 8192
#define NQ 8
#define KB 1024
#define TT 64
#define NTHR 512

#define OUT_CODES (B_ * D_ * T_)      // 16777216
#define OUT_BW (OUT_CODES + NQ * B_ * T_)
#define OUT_LOSS (OUT_BW + 1)

// rs: 64 rows x 512 halves (h1 granules 0..31, true-lo granules 32..63),
// granule (8 halves) swizzled: stored at g ^ (t & 7). No pad.
#define R_BYTES 65536
#define RED_OFF R_BYTES               // redv[256] f32 (8 waves x 32 rows)
#define REDI_OFF (RED_OFF + 1024)     // redi[256] i32
#define WSUM_OFF (REDI_OFF + 1024)    // wsum[8]
#define LDS_TOTAL (WSUM_OFF + 32)     // 67648 -> 2 blocks/CU

// workspace layout
#define WS_HI (8192 * 4)              // csq first (32KB)
#define CBW_HALVES (NQ * 8 * KB * 32) // 2,097,152 halves per array
#define WS_LO (WS_HI + CBW_HALVES * 2)

// ---------------- init: codebook row norms (fp32) + scalar outputs ----------------
__global__ void init_cbsq_kernel(const float* __restrict__ cb, const int* __restrict__ sr,
                                 float* __restrict__ csq, float* __restrict__ out) {
    int gid = blockIdx.x * blockDim.x + threadIdx.x;
    int row = gid >> 6;
    int lane = gid & 63;
    float4 v = ((const float4*)(cb + (size_t)row * D_))[lane];
    float s = fmaf(v.x, v.x, fmaf(v.y, v.y, fmaf(v.z, v.z, v.w * v.w)));
#pragma unroll
    for (int off = 32; off; off >>= 1) s += __shfl_down(s, off);
    if (lane == 0) csq[row] = s;
    if (gid == 0) {
        out[OUT_BW] = (float)(*sr) * (80.0f / 1000.0f);
        out[OUT_LOSS] = 0.0f;
    }
}

// ---------------- init: split codebook into f16 hi + TRUE lo, [q][dc8][code][32] ----------------
__global__ void init_split_kernel(const float* __restrict__ cb, f16* __restrict__ whi,
                                  f16* __restrict__ wlo) {
    int gid = blockIdx.x * 256 + threadIdx.x;   // (q*8+dc)*1024 + k
    int qdc = gid >> 10, k = gid & 1023;
    int q = qdc >> 3, dc = qdc & 7;
    const float* src = cb + ((size_t)(q * 1024 + k)) * 256 + dc * 32;
    size_t wo = (size_t)gid * 32;
#pragma unroll
    for (int jj = 0; jj < 4; ++jj) {
        float4 a = ((const float4*)src)[jj * 2];
        float4 c = ((const float4*)src)[jj * 2 + 1];
        float vals[8] = {a.x, a.y, a.z, a.w, c.x, c.y, c.z, c.w};
        f16x8 hv, lv;
#pragma unroll
        for (int i = 0; i < 8; ++i) {
            f16 h = (f16)vals[i];
            hv[i] = h;
            lv[i] = (f16)(vals[i] - (float)h);    // true lo (f16 subnormals cover it)
        }
        *(f16x8*)&whi[wo + jj * 8] = hv;
        *(f16x8*)&wlo[wo + jj * 8] = lv;
    }
}

// ---------------- main RVQ kernel: 3-product split-f16 MFMA GEMM, single accumulator ----------------
// dot = (ahi+alo)·(bhi+blo) ≈ ahi·bhi + alo·bhi + ahi·blo, all accumulated into one
// fp32 acc at natural scale (cross terms ~2^-11 relative; rounding below noise floor).
// 8 waves = 2 row-halves (wm) x 4 code-stripes (wn); 32 acc VGPR/wave, ~90 total
// -> fits 128-unified cap -> 4 waves/SIMD (16/CU) at 2 blocks/CU.
extern "C" __global__ __launch_bounds__(NTHR, 4)
void rvq_kernel(const float* __restrict__ x, const float* __restrict__ cb,
                const float* __restrict__ csq, const f16* __restrict__ whi,
                const f16* __restrict__ wlo, float* __restrict__ out) {
    extern __shared__ char smem[];
    f16* rs = (f16*)smem;                          // [64][512] halves, granule-swizzled
    float* redv = (float*)(smem + RED_OFF);
    int* redi = (int*)(smem + REDI_OFF);
    float* wsum = (float*)(smem + WSUM_OFF);

    const int tid = threadIdx.x;
    const int w = tid >> 6;
    const int l = tid & 63;
    const int l15 = l & 15;
    const int q4 = l >> 4;
    const int wm = w >> 2;        // row half: rows [wm*32, wm*32+32)
    const int wn = w & 3;         // code stripe within sweep

    const int b = blockIdx.x >> 7;
    const int t0 = (blockIdx.x & 127) * TT;
    const float* xb = x + (size_t)b * D_ * T_;

    // residual init: rs[t][d] split of x[b][d][t0+t] (coalesced over t); swizzled store
    for (int d = tid >> 6; d < D_; d += 8) {
        float v = xb[(size_t)d * T_ + t0 + l];
        f16 h = (f16)v;
        const int sw = l & 7;
        rs[l * 512 + (((d >> 3) ^ sw) << 3) + (d & 7)] = h;
        rs[l * 512 + ((((d >> 3) + 32) ^ sw) << 3) + (d & 7)] = (f16)(v - (float)h);
    }

    float ssq = 0.0f;

    for (int q = 0; q < NQ; ++q) {
        const float* cbq = cb + (size_t)q * KB * D_;
        const char* wq = (const char*)(whi + (size_t)q * 8 * KB * 32);
        const char* lq = (const char*)(wlo + (size_t)q * 8 * KB * 32);

        __syncthreads();   // rs ready (init or prev-q update); redv/redi free for this q

        // cross-sweep running best, per-lane registers (slot = (mt,rg) row ownership,
        // sweep-invariant; codes ascend across sweeps -> strict < keeps first min)
        float bval[8];
        int bidx[8];
#pragma unroll
        for (int e = 0; e < 8; ++e) { bval[e] = INFINITY; bidx[e] = 0; }

        const int swA = l15 & 7;                   // == t&7 for all A rows of this lane

        for (int s = 0; s < 4; ++s) {              // 4 sweeps of 256 codes; stripe/wave = 64
            // per-lane byte base into [code][32] tile: code*64 + q4*16
            const int vbase = ((s * 256 + wn * 64 + l15) << 6) + q4 * 16;

            f32x4 ah[2][4];                        // 32 acc VGPRs
#pragma unroll
            for (int mt = 0; mt < 2; ++mt)
#pragma unroll
                for (int nt = 0; nt < 4; ++nt) ah[mt][nt] = (f32x4)0.0f;

#pragma unroll 1
            for (int dc = 0; dc < 8; ++dc) {
                const int ga = dc * 4 + q4;        // h1 granule (true-lo = +32)
                f16x8 af1[2], af2[2];
#pragma unroll
                for (int mt = 0; mt < 2; ++mt) {
                    const f16* rowp = rs + (wm * 32 + mt * 16 + l15) * 512;
                    af1[mt] = *(const f16x8*)&rowp[(ga ^ swA) << 3];
                    af2[mt] = *(const f16x8*)&rowp[((ga + 32) ^ swA) << 3];
                }
                const char* wqd = wq + dc * 65536;
                const char* lqd = lq + dc * 65536;
#pragma unroll
                for (int nt = 0; nt < 4; ++nt) {
                    const int off = vbase + nt * 1024;
                    const f16x8 cb1 = *(const f16x8*)(wqd + off);
                    const f16x8 cb2 = *(const f16x8*)(lqd + off);
#pragma unroll
                    for (int mt = 0; mt < 2; ++mt) {
                        ah[mt][nt] = __builtin_amdgcn_mfma_f32_16x16x32_f16(af1[mt], cb1, ah[mt][nt], 0, 0, 0);
                        ah[mt][nt] = __builtin_amdgcn_mfma_f32_16x16x32_f16(af2[mt], cb1, ah[mt][nt], 0, 0, 0);
                        ah[mt][nt] = __builtin_amdgcn_mfma_f32_16x16x32_f16(af1[mt], cb2, ah[mt][nt], 0, 0, 0);
                    }
                }
            }
            // fold sweep into cross-sweep per-lane best (codes ascending -> strict <)
            const int cbase = s * 256 + wn * 64 + l15;
#pragma unroll
            for (int nt = 0; nt < 4; ++nt) {
                const int code = cbase + nt * 16;
                const float cq = csq[q * KB + code];
#pragma unroll
                for (int mt = 0; mt < 2; ++mt)
#pragma unroll
                    for (int rg = 0; rg < 4; ++rg) {
                        const float dist = fmaf(-2.0f, ah[mt][nt][rg], cq);
                        const int e = mt * 4 + rg;
                        if (dist < bval[e]) { bval[e] = dist; bidx[e] = code; }
                    }
            }
        }
        // once per q: butterfly across the 16 lanes sharing each row
#pragma unroll
        for (int m = 1; m < 16; m <<= 1) {
#pragma unroll
            for (int e = 0; e < 8; ++e) {
                const float ov = __shfl_xor(bval[e], m);
                const int oi = __shfl_xor(bidx[e], m);
                if (ov < bval[e] || (ov == bval[e] && oi < bidx[e])) { bval[e] = ov; bidx[e] = oi; }
            }
        }
        if (l15 == 0) {
#pragma unroll
            for (int mt = 0; mt < 2; ++mt)
#pragma unroll
                for (int rg = 0; rg < 4; ++rg) {
                    const int tl = mt * 16 + q4 * 4 + rg;   // row within wm half (C layout)
                    redv[w * 32 + tl] = bval[mt * 4 + rg];
                    redi[w * 32 + tl] = bidx[mt * 4 + rg];
                }
        }
        __syncthreads();   // all waves' redv/redi final; all GEMM rs reads done
        // merged final-reduce + residual update: thread -> (row t, 32-half chunk ch)
        {
            const int t = tid & 63, ch = tid >> 6;
            const int wmr = t >> 5, tl = t & 31;
            float bv = redv[(wmr * 4) * 32 + tl];
            int bi = redi[(wmr * 4) * 32 + tl];
#pragma unroll
            for (int w2 = 1; w2 < 4; ++w2) {
                const float v = redv[(wmr * 4 + w2) * 32 + tl];
                const int ii = redi[(wmr * 4 + w2) * 32 + tl];
                if (v < bv || (v == bv && ii < bi)) { bv = v; bi = ii; }
            }
            if (ch == 0) out[OUT_CODES + ((size_t)q * B_ + b) * T_ + t0 + t] = (float)bi;
            // residual update: fp32 = h1 + lo, subtract cb row, re-split; ssq
            const float* crow = cbq + (size_t)bi * D_ + ch * 32;
            f16* rowp = rs + t * 512;
            const int sw = t & 7;
#pragma unroll
            for (int jj = 0; jj < 4; ++jj) {
                const int g = ch * 4 + jj;
                const int g1 = (g ^ sw) << 3;
                const int g2 = ((g + 32) ^ sw) << 3;
                f16x8 hv = *(const f16x8*)&rowp[g1];
                f16x8 lv = *(const f16x8*)&rowp[g2];
                const float4 c0 = ((const float4*)crow)[jj * 2];
                const float4 c1 = ((const float4*)crow)[jj * 2 + 1];
                const float cc[8] = {c0.x, c0.y, c0.z, c0.w, c1.x, c1.y, c1.z, c1.w};
                f16x8 nh, nl;
#pragma unroll
                for (int i = 0; i < 8; ++i) {
                    const float r = (float)hv[i] + (float)lv[i];
                    const float nv = r - cc[i];
                    ssq = fmaf(nv, nv, ssq);
                    const f16 h = (f16)nv;
                    nh[i] = h;
                    nl[i] = (f16)(nv - (float)h);
                }
                *(f16x8*)&rowp[g1] = nh;
                *(f16x8*)&rowp[g2] = nl;
            }
        }
        // next q's top __syncthreads orders rs writes before A-frag reads
    }
    __syncthreads();
    // quantized = x - r_final, [B][D][T], coalesced over t
    {
        float* outq = out + (size_t)b * D_ * T_;
        for (int d = tid >> 6; d < D_; d += 8) {
            const int sw = l & 7;
            const float h1 = (float)rs[l * 512 + (((d >> 3) ^ sw) << 3) + (d & 7)];
            const float h2 = (float)rs[l * 512 + ((((d >> 3) + 32) ^ sw) << 3) + (d & 7)];
            const size_t gi = (size_t)d * T_ + t0 + l;
            outq[gi] = xb[gi] - (h1 + h2);
        }
    }
    // commit loss: wave reduce -> block reduce -> one atomic
#pragma unroll
    for (int off = 32; off; off >>= 1) ssq += __shfl_down(ssq, off);
    if (l == 0) wsum[w] = ssq;
    __syncthreads();
    if (tid == 0) {
        float tot = 0.0f;
#pragma unroll
        for (int i = 0; i < 8; ++i) tot += wsum[i];
        const float scale = 0.25f / ((float)NQ * (float)B_ * (float)D_ * (float)T_);
        atomicAdd(out + OUT_LOSS, tot * scale);
    }
}

extern "C" void kernel_launch(void* const* d_in, const int* in_sizes, int n_in,
                              void* d_out, int out_size, void* d_ws, size_t ws_size,
                              hipStream_t stream) {
    const float* x = (const float*)d_in[0];
    const int* sr = (const int*)d_in[1];
    const float* cb = (const float*)d_in[2];
    float* out = (float*)d_out;
    float* csq = (float*)d_ws;
    f16* whi = (f16*)((char*)d_ws + WS_HI);
    f16* wlo = (f16*)((char*)d_ws + WS_LO);

    hipFuncSetAttribute((const void*)rvq_kernel, hipFuncAttributeMaxDynamicSharedMemorySize,
                        LDS_TOTAL);

    init_cbsq_kernel<<<2048, 256, 0, stream>>>(cb, sr, csq, out);
    init_split_kernel<<<256, 256, 0, stream>>>(cb, whi, wlo);
    rvq_kernel<<<B_ * (T_ / TT), NTHR, LDS_TOTAL, stream>>>(x, cb, csq, whi, wlo, out);
}